// Round 2
// baseline (3503.871 us; speedup 1.0000x reference)
//
#include <hip/hip_runtime.h>
#include <stdint.h>

#define B_  128
#define T_  1024
#define H_  512
#define I_  64
#define TB_ 131072   // T_*B_

typedef _Float16 half2_t __attribute__((ext_vector_type(2)));
typedef uint32_t u32v32  __attribute__((ext_vector_type(32)));

union U32H2 { uint32_t u; half2_t h; };
union U16H  { uint16_t u; _Float16 h; };

static __device__ __forceinline__ half2_t u2h(uint32_t u){ U32H2 x; x.u=u; return x.h; }
static __device__ __forceinline__ uint32_t h2u(half2_t h){ U32H2 x; x.h=h; return x.u; }

#if defined(__has_builtin)
#if __has_builtin(__builtin_amdgcn_fdot2)
#define HAVE_FDOT2 1
#endif
#endif

static __device__ __forceinline__ float fdot2f(half2_t a, half2_t b, float c){
#ifdef HAVE_FDOT2
    return __builtin_amdgcn_fdot2(a, b, c, false);
#else
    return c + (float)a[0]*(float)b[0] + (float)a[1]*(float)b[1];
#endif
}

// ---------------------------------------------------------------------------
// Kernel A (fused): r[t*128+b][j] = (x[b][t][:] . W_in[j][:]) + sigma[j][t*128+b]
// written as f16. grid T_=1024 blocks, 512 threads. Per block: one t,
// all 128 b x 512 j. fp32 register-blocked compute with b128 LDS reads.
// Thread (tm=tid&31, tg=tid>>5): mi = tm+32*rr (rr<4), j = ch*256+tg*16+jj (jj<16).
// ---------------------------------------------------------------------------
#define PADA 68   // floats/row: 16B-aligned; row quad-bank = row%8 -> even spread

__global__ __attribute__((amdgpu_flat_work_group_size(512,512)))
void k_prep(const float* __restrict__ x, const float* __restrict__ Win,
            const float* __restrict__ sigma, uint32_t* __restrict__ r2)
{
    extern __shared__ float smemA[];
    float* As = smemA;               // [128][PADA]
    float* Ws = smemA + 128*PADA;    // [256][PADA]

    const int t   = blockIdx.x;
    const int tid = threadIdx.x;
    const int tm  = tid & 31;
    const int tg  = tid >> 5;        // [0,16)

    // stage x[b][t][0:64] -> As[b][:]  (2048 float4 units / 512 thr)
#pragma unroll
    for (int k = 0; k < 4; k++){
        int qid = k*512 + tid;
        int row = qid >> 4, qq = qid & 15;
        float4 v = *(const float4*)(x + ((size_t)row*T_ + t)*I_ + qq*4);
        *(float4*)(As + row*PADA + qq*4) = v;
    }

    for (int ch = 0; ch < 2; ch++){
        const int j0 = ch*256;
        __syncthreads();
        // stage W_in rows j0..j0+255 -> Ws
#pragma unroll
        for (int k = 0; k < 8; k++){
            int qid = k*512 + tid;
            int row = qid >> 4, qq = qid & 15;
            float4 v = *(const float4*)(Win + (size_t)(j0+row)*I_ + qq*4);
            *(float4*)(Ws + row*PADA + qq*4) = v;
        }
        __syncthreads();

        float acc[4][16];
#pragma unroll
        for (int rr=0;rr<4;rr++)
#pragma unroll
            for (int jj=0;jj<16;jj++) acc[rr][jj] = 0.f;

#pragma unroll
        for (int ic = 0; ic < 16; ic++){
            float4 a4[4];
#pragma unroll
            for (int rr=0;rr<4;rr++)
                a4[rr] = *(const float4*)(As + (size_t)(tm+32*rr)*PADA + ic*4);
#pragma unroll
            for (int jj=0;jj<16;jj++){
                float4 wv = *(const float4*)(Ws + (size_t)(tg*16+jj)*PADA + ic*4); // broadcast
#pragma unroll
                for (int rr=0;rr<4;rr++)
                    acc[rr][jj] += a4[rr].x*wv.x + a4[rr].y*wv.y
                                 + a4[rr].z*wv.z + a4[rr].w*wv.w;
            }
        }

        // epilogue: + sigma (coalesced: lanes tm consecutive mi), write f16 uint4
#pragma unroll
        for (int rr=0; rr<4; rr++){
            const size_t mi = (size_t)t*128 + tm + 32*rr;
            const float* sp = sigma + (size_t)(j0 + tg*16)*TB_ + mi;
            uint32_t ou[8];
#pragma unroll
            for (int k2=0;k2<8;k2++){
                float sA = sp[(size_t)(2*k2  )*TB_];
                float sB = sp[(size_t)(2*k2+1)*TB_];
                half2_t hv;
                hv[0] = (_Float16)(acc[rr][2*k2  ] + sA);
                hv[1] = (_Float16)(acc[rr][2*k2+1] + sB);
                ou[k2] = h2u(hv);
            }
            uint32_t* dst = r2 + mi*256 + (j0>>1) + tg*8;
            uint4 q0 = make_uint4(ou[0],ou[1],ou[2],ou[3]);
            uint4 q1 = make_uint4(ou[4],ou[5],ou[6],ou[7]);
            *(uint4*)(dst)     = q0;
            *(uint4*)(dst + 4) = q1;
        }
    }
}

// ---------------------------------------------------------------------------
// Kernel B: the recurrence. One workgroup per batch column b. 512 threads.
// Thread t = (wave w, lane l): k-chunk [64w,64w+64); rows {l+64m, m<8}.
// W f16: rows m<6 in SIX ext_vector_type(32) SSA values (192 VGPRs, spill-proof),
// rows 6,7 in LDS (rotated, b128). waves_per_eu(2,2): exactly our 8-wave block,
// VGPR budget 256 — do NOT let the allocator target higher occupancy (r1: it
// capped at 128 and spilled W to scratch -> 2 ms).
// ---------------------------------------------------------------------------
__global__ __attribute__((amdgpu_flat_work_group_size(512,512)))
           __attribute__((amdgpu_waves_per_eu(2,2)))
void k_rnn(const float* __restrict__ Wh,
           const float* __restrict__ Win,
           const float* __restrict__ x,
           const float* __restrict__ sigma,
           const float* __restrict__ h0,
           const uint16_t* __restrict__ r16,
           float* __restrict__ out,
           int use_r)
{
    extern __shared__ char smem[];
    uint32_t*  WL  = (uint32_t*)smem;                // [512*64] u32 (f16x2), 128 KB
    float*     par = (float*)(smem + 131072);        // [8*512] partials, 16 KB
    _Float16*  sb  = (_Float16*)(smem + 147456);     // [512] sigmoid(h), 1 KB

    const int b = blockIdx.x;
    const int t = threadIdx.x;
    const int w = t >> 6;
    const int l = t & 63;
    const int j = t;
    const int phase = (l & 15) << 2;   // pair rotation, multiple of 4 -> b128 contiguous

    // rows m=0..5 -> register vectors (one-time load + f16 convert)
    u32v32 w0, w1, w2, w3, w4, w5;
#define LOADR(VM, M) { \
    const float4* wr = (const float4*)(Wh + (size_t)(l + 64*(M))*H_ + (w << 6)); \
    _Pragma("unroll") \
    for (int q = 0; q < 16; q++){ \
        float4 v = wr[q]; \
        half2_t a;  a[0]=(_Float16)v.x;  a[1]=(_Float16)v.y; \
        half2_t c2; c2[0]=(_Float16)v.z; c2[1]=(_Float16)v.w; \
        VM[2*q]   = h2u(a); \
        VM[2*q+1] = h2u(c2); \
    } }
    LOADR(w0, 0) LOADR(w1, 1) LOADR(w2, 2)
    LOADR(w3, 3) LOADR(w4, 4) LOADR(w5, 5)
#undef LOADR

    // rows m=6,7 -> LDS (rotated so b128 reads spread quad-banks)
#pragma unroll
    for (int m = 6; m < 8; m++){
        const float4* wr = (const float4*)(Wh + (size_t)(l + 64*m)*H_ + (w << 6));
#pragma unroll
        for (int q = 0; q < 16; q++){
            float4 v = wr[q];
            half2_t a;  a[0]=(_Float16)v.x;  a[1]=(_Float16)v.y;
            half2_t c2; c2[0]=(_Float16)v.z; c2[1]=(_Float16)v.w;
            int base = (m-6)*32, pp = 2*q;
            WL[t*64 + ((base + pp     + phase) & 63)] = h2u(a);
            WL[t*64 + ((base + pp + 1 + phase) & 63)] = h2u(c2);
        }
    }

    float h = h0[(size_t)j*B_ + b];
    const uint32_t* WLt = WL + t*64;
    const uint32_t* sbu = (const uint32_t*)sb;
    float* outp = out + (size_t)b*T_*H_ + j;
    const uint16_t* rp = r16 + (size_t)b*H_ + j;   // element (ts*128+b)*512 + j

    for (int ts = 0; ts < T_; ts++){
        // prefetch this step's r (consumed after the dot phase)
        uint16_t ru = 0;
        if (use_r) ru = rp[(size_t)ts * 65536];

        float e = __expf(-h);
        float s = 1.0f / (1.0f + e);
        sb[j] = (_Float16)s;
        __syncthreads();

        float p[8];
#pragma unroll
        for (int m = 0; m < 8; m++) p[m] = 0.f;

#pragma unroll
        for (int cc = 0; cc < 8; cc++){
            uint4 sq = *(const uint4*)(sbu + (w << 5) + (cc << 2));  // wave-uniform broadcast
            half2_t s0=u2h(sq.x), s1=u2h(sq.y), s2=u2h(sq.z), s3=u2h(sq.w);
            uint4 q6 = *(const uint4*)(WLt + ((4*cc      + phase) & 63));
            uint4 q7 = *(const uint4*)(WLt + ((32 + 4*cc + phase) & 63));
#define DOT4(VM, PM) \
            p[PM] = fdot2f(u2h(VM[4*cc+0]), s0, p[PM]); \
            p[PM] = fdot2f(u2h(VM[4*cc+1]), s1, p[PM]); \
            p[PM] = fdot2f(u2h(VM[4*cc+2]), s2, p[PM]); \
            p[PM] = fdot2f(u2h(VM[4*cc+3]), s3, p[PM]);
            DOT4(w0, 0) DOT4(w1, 1) DOT4(w2, 2)
            DOT4(w3, 3) DOT4(w4, 4) DOT4(w5, 5)
#undef DOT4
            p[6] = fdot2f(u2h(q6.x), s0, p[6]);
            p[6] = fdot2f(u2h(q6.y), s1, p[6]);
            p[6] = fdot2f(u2h(q6.z), s2, p[6]);
            p[6] = fdot2f(u2h(q6.w), s3, p[6]);
            p[7] = fdot2f(u2h(q7.x), s0, p[7]);
            p[7] = fdot2f(u2h(q7.y), s1, p[7]);
            p[7] = fdot2f(u2h(q7.z), s2, p[7]);
            p[7] = fdot2f(u2h(q7.w), s3, p[7]);
        }

#pragma unroll
        for (int m = 0; m < 8; m++) par[(w << 9) + l + (m << 6)] = p[m];
        __syncthreads();

        float P = par[j] + par[j+512] + par[j+1024] + par[j+1536]
                + par[j+2048] + par[j+2560] + par[j+3072] + par[j+3584];

        float rv;
        if (use_r){
            U16H cv; cv.u = ru;
            rv = (float)cv.h;
        } else {
            // fallback: w_in inline + scattered sigma (correct but slow)
            float acc = 0.f;
            const float4* wir = (const float4*)(Win + (size_t)j*I_);
            const float4* xr  = (const float4*)(x + ((size_t)b*T_ + ts)*I_);
#pragma unroll
            for (int q = 0; q < 16; q++){
                float4 a = wir[q]; float4 xx = xr[q];
                acc += a.x*xx.x + a.y*xx.y + a.z*xx.z + a.w*xx.w;
            }
            rv = acc + sigma[((size_t)j << 17) + (ts << 7) + b];
        }

        h = 0.9f*h + 0.1f*(P + rv);
        outp[(size_t)ts * H_] = h;
    }

    // h_last[j][b]
    out[(size_t)B_*T_*H_ + (size_t)j*B_ + b] = h;
}

// ---------------------------------------------------------------------------
extern "C" void kernel_launch(void* const* d_in, const int* in_sizes, int n_in,
                              void* d_out, int out_size, void* d_ws, size_t ws_size,
                              hipStream_t stream)
{
    const float* x     = (const float*)d_in[0];
    const float* Win   = (const float*)d_in[1];
    const float* Wh    = (const float*)d_in[2];
    const float* sigma = (const float*)d_in[3];
    const float* h0    = (const float*)d_in[4];
    float* out = (float*)d_out;

    const size_t r_bytes = (size_t)TB_ * H_ * 2;   // 134,217,728 B (f16 r)
    const int use_r = (ws_size >= r_bytes) ? 1 : 0;

    if (use_r){
        const int prep_lds = (128 + 256) * PADA * 4;   // 104,448 B
        (void)hipFuncSetAttribute((const void*)k_prep,
                                  hipFuncAttributeMaxDynamicSharedMemorySize, prep_lds);
        k_prep<<<T_, 512, prep_lds, stream>>>(x, Win, sigma, (uint32_t*)d_ws);
    }

    const int lds_bytes = 131072 + 16384 + 1024;   // 148,480
    (void)hipFuncSetAttribute((const void*)k_rnn,
                              hipFuncAttributeMaxDynamicSharedMemorySize, lds_bytes);
    k_rnn<<<B_, 512, lds_bytes, stream>>>(Wh, Win, x, sigma, h0,
                                          (const uint16_t*)d_ws, out, use_r);
}